// Round 1
// baseline (4958.679 us; speedup 1.0000x reference)
//
#include <hip/hip_runtime.h>
#include <math.h>

#define THREADS 256
#define TM 16

// ---------------------------------------------------------------------------
// Kernel A: per-row L2 norm reciprocal.  One wave per row.
// rnorm[i] = 1 / max(||x_i||, 1e-12)
// ---------------------------------------------------------------------------
__global__ __launch_bounds__(THREADS) void k_rownorm(const float* __restrict__ x,
                                                     float* __restrict__ rnorm,
                                                     int B, int D) {
  const int wave = threadIdx.x >> 6;
  const int lane = threadIdx.x & 63;
  const int row = blockIdx.x * 4 + wave;
  if (row >= B) return;
  const float4* xr = reinterpret_cast<const float4*>(x + (size_t)row * D);
  const int nv = D >> 2;
  float s = 0.f;
  for (int t = lane; t < nv; t += 64) {
    float4 v = xr[t];
    s += v.x * v.x + v.y * v.y + v.z * v.z + v.w * v.w;
  }
  #pragma unroll
  for (int off = 32; off; off >>= 1) s += __shfl_xor(s, off);
  if (lane == 0) {
    float n = sqrtf(s);
    rnorm[row] = 1.0f / fmaxf(n, 1e-12f);
  }
}

// ---------------------------------------------------------------------------
// Kernel B: normalized transpose  xT[k*B + i] = x[i*D + k] * rnorm[i]
// 64x64 tiles via LDS, both read and write coalesced.
// ---------------------------------------------------------------------------
__global__ __launch_bounds__(THREADS) void k_transpose(const float* __restrict__ x,
                                                       const float* __restrict__ rnorm,
                                                       float* __restrict__ xT,
                                                       int B, int D) {
  __shared__ float tile[64][65];
  const int i0 = blockIdx.x * 64;
  const int k0 = blockIdx.y * 64;
  const int tid = threadIdx.x;
  const int lr = tid >> 6;   // 0..3
  const int lc = tid & 63;   // 0..63
  #pragma unroll
  for (int p = 0; p < 16; ++p) {
    const int li = p * 4 + lr;
    tile[li][lc] = x[(size_t)(i0 + li) * D + (k0 + lc)];
  }
  __syncthreads();
  const float rn = rnorm[i0 + lc];
  #pragma unroll
  for (int p = 0; p < 16; ++p) {
    const int lk = p * 4 + lr;
    xT[(size_t)(k0 + lk) * B + (i0 + lc)] = tile[lc][lk] * rn;
  }
}

// ---------------------------------------------------------------------------
// Kernel C: fused sim-row + online dual logsumexp.
// Block = 256 threads, owns TM=16 rows. LDS holds the 16 normalized rows
// (exactly 64 KB). Each thread owns one column j per 256-wide chunk and
// keeps online (m,s) LSE state for pos/neg logits of all 16 rows.
// Masked (NEG_FILL) entries contribute exp(-1e4 - m) == 0 in fp32 for any
// valid row, so skipping them is exact; rows with no pos or no neg get a
// -1 sentinel (loss >= 0 always for real rows).
// ---------------------------------------------------------------------------
__global__ __launch_bounds__(THREADS) void k_main(const float* __restrict__ x,
                                                  const float* __restrict__ rnorm,
                                                  const float* __restrict__ xT,
                                                  const int* __restrict__ tgt,
                                                  float* __restrict__ row_loss,
                                                  int B, int D) {
  __shared__ __align__(16) float xi[TM * 1024];  // 64 KB, D must be 1024
  const int tid = threadIdx.x;
  const int i0 = blockIdx.x * TM;

  // Stage 16 normalized rows into LDS (coalesced float4 per row).
  #pragma unroll
  for (int r = 0; r < TM; ++r) {
    const float rn = rnorm[i0 + r];
    float4 v = reinterpret_cast<const float4*>(x + (size_t)(i0 + r) * D)[tid];
    v.x *= rn; v.y *= rn; v.z *= rn; v.w *= rn;
    reinterpret_cast<float4*>(xi + r * 1024)[tid] = v;
  }
  int tgts[TM];
  #pragma unroll
  for (int r = 0; r < TM; ++r) tgts[r] = tgt[i0 + r];  // uniform -> scalar loads
  __syncthreads();

  float mp[TM], sp[TM], mn[TM], sn[TM];
  #pragma unroll
  for (int r = 0; r < TM; ++r) { mp[r] = -1e30f; mn[r] = -1e30f; sp[r] = 0.f; sn[r] = 0.f; }

  const int nchunk = B / THREADS;
  for (int c = 0; c < nchunk; ++c) {
    const int j = c * THREADS + tid;
    const int tj = tgt[j];
    const float* xTj = xT + j;
    float acc[TM];
    #pragma unroll
    for (int r = 0; r < TM; ++r) acc[r] = 0.f;

    #pragma unroll 2
    for (int k4 = 0; k4 < 256; ++k4) {
      const size_t base = (size_t)(k4 * 4) * B;
      const float v0 = xTj[base];
      const float v1 = xTj[base + B];
      const float v2 = xTj[base + 2 * (size_t)B];
      const float v3 = xTj[base + 3 * (size_t)B];
      #pragma unroll
      for (int r = 0; r < TM; ++r) {
        const float4 a = reinterpret_cast<const float4*>(xi + r * 1024)[k4];
        acc[r] = fmaf(a.x, v0, acc[r]);
        acc[r] = fmaf(a.y, v1, acc[r]);
        acc[r] = fmaf(a.z, v2, acc[r]);
        acc[r] = fmaf(a.w, v3, acc[r]);
      }
    }

    // Epilogue: online LSE update for pos and neg logits.
    #pragma unroll
    for (int r = 0; r < TM; ++r) {
      const float sim = acc[r];
      const bool same = (tj == tgts[r]);
      const bool diag = (j == i0 + r);
      {  // positive: same target, not diagonal
        const bool v = same && !diag;
        const float ap = fmaxf(1.25f - sim, 0.f);
        const float l = -ap * (sim - 0.75f) * 64.f;
        const float nm = v ? fmaxf(mp[r], l) : mp[r];
        sp[r] = sp[r] * __expf(mp[r] - nm) + (v ? __expf(l - nm) : 0.f);
        mp[r] = nm;
      }
      {  // negative: different target
        const bool v = !same;
        const float an = fmaxf(sim + 0.25f, 0.f);
        const float l = an * (sim - 0.25f) * 64.f;
        const float nm = v ? fmaxf(mn[r], l) : mn[r];
        sn[r] = sn[r] * __expf(mn[r] - nm) + (v ? __expf(l - nm) : 0.f);
        mn[r] = nm;
      }
    }
  }

  // Reduce (m,s) pairs across the 64 lanes of each wave.
  #pragma unroll
  for (int r = 0; r < TM; ++r) {
    for (int off = 32; off; off >>= 1) {
      float m2 = __shfl_xor(mp[r], off);
      float s2 = __shfl_xor(sp[r], off);
      float nm = fmaxf(mp[r], m2);
      sp[r] = sp[r] * __expf(mp[r] - nm) + s2 * __expf(m2 - nm);
      mp[r] = nm;
      m2 = __shfl_xor(mn[r], off);
      s2 = __shfl_xor(sn[r], off);
      nm = fmaxf(mn[r], m2);
      sn[r] = sn[r] * __expf(mn[r] - nm) + s2 * __expf(m2 - nm);
      mn[r] = nm;
    }
  }

  __syncthreads();           // all waves finished reading xi
  float* red = xi;           // alias: [4 waves][TM][4]
  const int wave = tid >> 6;
  const int lane = tid & 63;
  if (lane == 0) {
    #pragma unroll
    for (int r = 0; r < TM; ++r) {
      float* p = red + ((wave * TM) + r) * 4;
      p[0] = mp[r]; p[1] = sp[r]; p[2] = mn[r]; p[3] = sn[r];
    }
  }
  __syncthreads();
  if (tid < TM) {
    float fmp = -1e30f, fsp = 0.f, fmn = -1e30f, fsn = 0.f;
    #pragma unroll
    for (int w = 0; w < 4; ++w) {
      const float* p = red + ((w * TM) + tid) * 4;
      float m2 = p[0], s2 = p[1];
      float nm = fmaxf(fmp, m2);
      fsp = fsp * __expf(fmp - nm) + s2 * __expf(m2 - nm);
      fmp = nm;
      m2 = p[2]; s2 = p[3];
      nm = fmaxf(fmn, m2);
      fsn = fsn * __expf(fmn - nm) + s2 * __expf(m2 - nm);
      fmn = nm;
    }
    const bool valid = (fsp > 0.f) && (fsn > 0.f);
    float loss = -1.0f;
    if (valid) {
      const float lp = fmp + logf(fsp);
      const float ln = fmn + logf(fsn);
      const float z = lp + ln;
      loss = (z > 0.f) ? (z + log1pf(__expf(-z))) : log1pf(__expf(z));
    }
    row_loss[i0 + tid] = loss;
  }
}

// ---------------------------------------------------------------------------
// Kernel D: masked mean over rows.  One block.
// ---------------------------------------------------------------------------
__global__ __launch_bounds__(THREADS) void k_final(const float* __restrict__ row_loss,
                                                   float* __restrict__ out, int B) {
  __shared__ float ssum[4];
  __shared__ float scnt[4];
  const int tid = threadIdx.x;
  float sum = 0.f, cnt = 0.f;
  for (int i = tid; i < B; i += THREADS) {
    const float l = row_loss[i];
    if (l >= 0.f) { sum += l; cnt += 1.f; }
  }
  #pragma unroll
  for (int off = 32; off; off >>= 1) {
    sum += __shfl_xor(sum, off);
    cnt += __shfl_xor(cnt, off);
  }
  const int wave = tid >> 6;
  const int lane = tid & 63;
  if (lane == 0) { ssum[wave] = sum; scnt[wave] = cnt; }
  __syncthreads();
  if (tid == 0) {
    float ts = 0.f, tc = 0.f;
    #pragma unroll
    for (int w = 0; w < 4; ++w) { ts += ssum[w]; tc += scnt[w]; }
    out[0] = ts / fmaxf(tc, 1.f);
  }
}

// ---------------------------------------------------------------------------
extern "C" void kernel_launch(void* const* d_in, const int* in_sizes, int n_in,
                              void* d_out, int out_size, void* d_ws, size_t ws_size,
                              hipStream_t stream) {
  const float* x = (const float*)d_in[0];
  const int* tgt = (const int*)d_in[1];
  float* out = (float*)d_out;
  const int B = in_sizes[1];
  const int D = in_sizes[0] / B;

  float* ws = (float*)d_ws;
  float* rnorm = ws;                          // B floats
  float* xT = ws + B;                         // D*B floats
  float* row_loss = xT + (size_t)D * B;       // B floats

  k_rownorm<<<B / 4, THREADS, 0, stream>>>(x, rnorm, B, D);
  dim3 tg(B / 64, D / 64);
  k_transpose<<<tg, THREADS, 0, stream>>>(x, rnorm, xT, B, D);
  k_main<<<B / TM, THREADS, 0, stream>>>(x, rnorm, xT, tgt, row_loss, B, D);
  k_final<<<1, THREADS, 0, stream>>>(row_loss, out, B);
}

// Round 2
// 302.317 us; speedup vs baseline: 16.4023x; 16.4023x over previous
//
#include <hip/hip_runtime.h>
#include <hip/hip_bf16.h>
#include <math.h>

#define THREADS 256
typedef unsigned short ushortT;
typedef __attribute__((ext_vector_type(8))) short bf16x8;   // 8 bf16 = 4 VGPRs
typedef __attribute__((ext_vector_type(4))) float f32x4;

__device__ __forceinline__ void async16(const ushortT* g, ushortT* l) {
  __builtin_amdgcn_global_load_lds(
      (const __attribute__((address_space(1))) unsigned int*)g,
      (__attribute__((address_space(3))) unsigned int*)l, 16, 0, 0);
}

// ---------------------------------------------------------------------------
// Kernel A: per-row L2 norm reciprocal. One wave per row.
// ---------------------------------------------------------------------------
__global__ __launch_bounds__(THREADS) void k_rownorm(const float* __restrict__ x,
                                                     float* __restrict__ rnorm,
                                                     int B, int D) {
  const int wave = threadIdx.x >> 6;
  const int lane = threadIdx.x & 63;
  const int row = blockIdx.x * 4 + wave;
  if (row >= B) return;
  const float4* xr = reinterpret_cast<const float4*>(x + (size_t)row * D);
  const int nv = D >> 2;
  float s = 0.f;
  for (int t = lane; t < nv; t += 64) {
    float4 v = xr[t];
    s += v.x * v.x + v.y * v.y + v.z * v.z + v.w * v.w;
  }
  #pragma unroll
  for (int off = 32; off; off >>= 1) s += __shfl_xor(s, off);
  if (lane == 0) rnorm[row] = 1.0f / fmaxf(sqrtf(s), 1e-12f);
}

// ---------------------------------------------------------------------------
// Kernel B: normalized bf16 copy. One block per row (256 thr x float4 = 1024).
// ---------------------------------------------------------------------------
__device__ __forceinline__ ushortT f2bf(float f) {
  __hip_bfloat16 h = __float2bfloat16(f);
  return *reinterpret_cast<ushortT*>(&h);
}

__global__ __launch_bounds__(THREADS) void k_prep(const float* __restrict__ x,
                                                  const float* __restrict__ rnorm,
                                                  ushortT* __restrict__ xn,
                                                  int B, int D) {
  const int row = blockIdx.x;
  const float rn = rnorm[row];
  const int gid = row * (D / 4) + threadIdx.x;
  float4 v = reinterpret_cast<const float4*>(x)[gid];
  ushort4 o;
  o.x = f2bf(v.x * rn); o.y = f2bf(v.y * rn);
  o.z = f2bf(v.z * rn); o.w = f2bf(v.w * rn);
  reinterpret_cast<ushort4*>(xn)[gid] = o;
}

// ---------------------------------------------------------------------------
// Kernel C: 128x128x1024 bf16 MFMA tile (m97 structure) + fused circle-loss
// epilogue producing per-row (m,s) LSE partials over this tile's 128 cols.
// Grid: (64 rowblocks, 64 colblocks). 4 waves, each computes a 64x64 region
// as 4x4 of 16x16x32 MFMA tiles. global_load_lds width=16 staging with
// XOR-swizzled k-chunks to break LDS bank conflicts on frag reads.
// partial[(i*64 + cb)*2 + half] = {mp, sp, mn, sn}
// ---------------------------------------------------------------------------
__global__ __launch_bounds__(THREADS, 2) void k_main_mfma(const ushortT* __restrict__ xn,
                                                          const int* __restrict__ tgt,
                                                          float4* __restrict__ partial,
                                                          int B, int D) {
  __shared__ ushortT Asm[128 * 32];  // 8 KB  [row][k] with swizzled k-chunks
  __shared__ ushortT Bsm[128 * 32];  // 8 KB

  const int tid = threadIdx.x;
  const int lane = tid & 63;
  const int w = tid >> 6;
  const int i0 = blockIdx.x * 128;   // row block
  const int j0 = blockIdx.y * 128;   // col block
  const int wr = (w >> 1) * 64;      // wave row offset in tile
  const int wc = (w & 1) * 64;       // wave col offset in tile

  // --- staging addresses (inst i covers rows i*16..i*16+15; wave w owns insts w, w+4)
  const int sr = lane >> 2;                 // row within 16-row group
  const int sc = (lane & 3) ^ (sr & 3);     // swizzled k-chunk fetched by this lane
  const ushortT* gA0 = xn + (size_t)(i0 + w * 16 + sr) * D + sc * 8;
  const ushortT* gA1 = xn + (size_t)(i0 + (w + 4) * 16 + sr) * D + sc * 8;
  const ushortT* gB0 = xn + (size_t)(j0 + w * 16 + sr) * D + sc * 8;
  const ushortT* gB1 = xn + (size_t)(j0 + (w + 4) * 16 + sr) * D + sc * 8;
  ushortT* lA0 = &Asm[w * 512];
  ushortT* lA1 = &Asm[(w + 4) * 512];
  ushortT* lB0 = &Bsm[w * 512];
  ushortT* lB1 = &Bsm[(w + 4) * 512];

  // --- fragment read offsets (undo the swizzle: stored chunk = logical ^ (row&3))
  const int fr = lane & 15;
  const int fk = (lane >> 4) ^ (fr & 3);
  const int aoff = (wr + fr) * 32 + fk * 8;
  const int boff = (wc + fr) * 32 + fk * 8;

  f32x4 acc[4][4];
  #pragma unroll
  for (int mt = 0; mt < 4; ++mt)
    #pragma unroll
    for (int nt = 0; nt < 4; ++nt)
      acc[mt][nt] = (f32x4){0.f, 0.f, 0.f, 0.f};

  const int kiters = D / 32;
  for (int kk = 0; kk < kiters; ++kk) {
    const size_t ko = (size_t)kk * 32;
    async16(gA0 + ko, lA0);
    async16(gA1 + ko, lA1);
    async16(gB0 + ko, lB0);
    async16(gB1 + ko, lB1);
    __syncthreads();
    bf16x8 afr[4], bfr[4];
    #pragma unroll
    for (int mt = 0; mt < 4; ++mt)
      afr[mt] = *reinterpret_cast<const bf16x8*>(&Asm[aoff + mt * 512]);
    #pragma unroll
    for (int nt = 0; nt < 4; ++nt)
      bfr[nt] = *reinterpret_cast<const bf16x8*>(&Bsm[boff + nt * 512]);
    #pragma unroll
    for (int mt = 0; mt < 4; ++mt)
      #pragma unroll
      for (int nt = 0; nt < 4; ++nt)
        acc[mt][nt] = __builtin_amdgcn_mfma_f32_16x16x32_bf16(afr[mt], bfr[nt], acc[mt][nt], 0, 0, 0);
    __syncthreads();
  }

  // --- epilogue: circle-loss logits + online LSE over this tile's 128 cols
  // C/D layout (16x16x32): col = lane&15, row = (lane>>4)*4 + reg
  const int cbase = j0 + wc + (lane & 15);
  int tj[4];
  #pragma unroll
  for (int nt = 0; nt < 4; ++nt) tj[nt] = tgt[cbase + nt * 16];

  #pragma unroll
  for (int mt = 0; mt < 4; ++mt) {
    #pragma unroll
    for (int reg = 0; reg < 4; ++reg) {
      const int i = i0 + wr + mt * 16 + (lane >> 4) * 4 + reg;
      const int ti = tgt[i];
      float mp = -1e30f, sp = 0.f, mn = -1e30f, sn = 0.f;
      #pragma unroll
      for (int nt = 0; nt < 4; ++nt) {
        const float sim = acc[mt][nt][reg];
        const int j = cbase + nt * 16;
        const bool same = (tj[nt] == ti);
        {  // positive: same target, not diagonal
          const bool v = same && (j != i);
          const float ap = fmaxf(1.25f - sim, 0.f);
          const float lg = -ap * (sim - 0.75f) * 64.f;
          const float nm = v ? fmaxf(mp, lg) : mp;
          sp = sp * __expf(mp - nm) + (v ? __expf(lg - nm) : 0.f);
          mp = nm;
        }
        {  // negative: different target
          const bool v = !same;
          const float an = fmaxf(sim + 0.25f, 0.f);
          const float lg = an * (sim - 0.25f) * 64.f;
          const float nm = v ? fmaxf(mn, lg) : mn;
          sn = sn * __expf(mn - nm) + (v ? __expf(lg - nm) : 0.f);
          mn = nm;
        }
      }
      // reduce across the 16 lanes holding the same row (lane&15 varies)
      #pragma unroll
      for (int off = 1; off < 16; off <<= 1) {
        float m2 = __shfl_xor(mp, off), s2 = __shfl_xor(sp, off);
        float nm = fmaxf(mp, m2);
        sp = sp * __expf(mp - nm) + s2 * __expf(m2 - nm);
        mp = nm;
        m2 = __shfl_xor(mn, off); s2 = __shfl_xor(sn, off);
        nm = fmaxf(mn, m2);
        sn = sn * __expf(mn - nm) + s2 * __expf(m2 - nm);
        mn = nm;
      }
      if ((lane & 15) == 0) {
        float4 o; o.x = mp; o.y = sp; o.z = mn; o.w = sn;
        partial[((size_t)i * 64 + blockIdx.y) * 2 + (w & 1)] = o;
      }
    }
  }
}

// ---------------------------------------------------------------------------
// Kernel D: fold 128 partials per row -> row loss. One wave per row.
// ---------------------------------------------------------------------------
__global__ __launch_bounds__(THREADS) void k_reduce(const float4* __restrict__ partial,
                                                    float* __restrict__ row_loss,
                                                    int B) {
  const int lane = threadIdx.x & 63;
  const int row = blockIdx.x * 4 + (threadIdx.x >> 6);
  const float4 a = partial[(size_t)row * 128 + lane];
  const float4 b = partial[(size_t)row * 128 + 64 + lane];
  float mp = fmaxf(a.x, b.x);
  float sp = a.y * __expf(a.x - mp) + b.y * __expf(b.x - mp);
  float mn = fmaxf(a.z, b.z);
  float sn = a.w * __expf(a.z - mn) + b.w * __expf(b.z - mn);
  #pragma unroll
  for (int off = 1; off < 64; off <<= 1) {
    float m2 = __shfl_xor(mp, off), s2 = __shfl_xor(sp, off);
    float nm = fmaxf(mp, m2);
    sp = sp * __expf(mp - nm) + s2 * __expf(m2 - nm);
    mp = nm;
    m2 = __shfl_xor(mn, off); s2 = __shfl_xor(sn, off);
    nm = fmaxf(mn, m2);
    sn = sn * __expf(mn - nm) + s2 * __expf(m2 - nm);
    mn = nm;
  }
  if (lane == 0) {
    float loss = -1.0f;
    if (sp > 0.f && sn > 0.f) {
      const float z = (mp + logf(sp)) + (mn + logf(sn));
      loss = (z > 0.f) ? (z + log1pf(__expf(-z))) : log1pf(__expf(z));
    }
    row_loss[row] = loss;
  }
}

// ---------------------------------------------------------------------------
// Kernel E: masked mean over rows. One block.
// ---------------------------------------------------------------------------
__global__ __launch_bounds__(THREADS) void k_final(const float* __restrict__ row_loss,
                                                   float* __restrict__ out, int B) {
  __shared__ float ssum[4];
  __shared__ float scnt[4];
  const int tid = threadIdx.x;
  float sum = 0.f, cnt = 0.f;
  for (int i = tid; i < B; i += THREADS) {
    const float l = row_loss[i];
    if (l >= 0.f) { sum += l; cnt += 1.f; }
  }
  #pragma unroll
  for (int off = 32; off; off >>= 1) {
    sum += __shfl_xor(sum, off);
    cnt += __shfl_xor(cnt, off);
  }
  const int wave = tid >> 6;
  const int lane = tid & 63;
  if (lane == 0) { ssum[wave] = sum; scnt[wave] = cnt; }
  __syncthreads();
  if (tid == 0) {
    float ts = 0.f, tc = 0.f;
    #pragma unroll
    for (int w = 0; w < 4; ++w) { ts += ssum[w]; tc += scnt[w]; }
    out[0] = ts / fmaxf(tc, 1.f);
  }
}

// ---------------------------------------------------------------------------
extern "C" void kernel_launch(void* const* d_in, const int* in_sizes, int n_in,
                              void* d_out, int out_size, void* d_ws, size_t ws_size,
                              hipStream_t stream) {
  const float* x = (const float*)d_in[0];
  const int* tgt = (const int*)d_in[1];
  float* out = (float*)d_out;
  const int B = in_sizes[1];
  const int D = in_sizes[0] / B;

  float* ws = (float*)d_ws;
  float* rnorm = ws;                                  // B floats
  float* row_loss = ws + B;                           // B floats
  ushortT* xn = (ushortT*)(ws + 2 * B);               // B*D bf16 (16 MB)
  float4* partial = (float4*)((char*)d_ws + (size_t)2 * B * 4 + (size_t)B * D * 2);  // B*128 float4 (16 MB)

  k_rownorm<<<B / 4, THREADS, 0, stream>>>(x, rnorm, B, D);
  k_prep<<<B, THREADS, 0, stream>>>(x, rnorm, xn, B, D);
  dim3 g(B / 128, B / 128);
  k_main_mfma<<<g, THREADS, 0, stream>>>(xn, tgt, partial, B, D);
  k_reduce<<<B / 4, THREADS, 0, stream>>>(partial, row_loss, B);
  k_final<<<1, THREADS, 0, stream>>>(row_loss, out, B);
}

// Round 3
// 250.426 us; speedup vs baseline: 19.8010x; 1.2072x over previous
//
#include <hip/hip_runtime.h>
#include <hip/hip_bf16.h>
#include <math.h>

#define THREADS 256
typedef unsigned short ushortT;
typedef __attribute__((ext_vector_type(8))) short bf16x8;   // 8 bf16 = 4 VGPRs
typedef __attribute__((ext_vector_type(4))) float f32x4;

__device__ __forceinline__ void async16(const ushortT* g, ushortT* l) {
  __builtin_amdgcn_global_load_lds(
      (const __attribute__((address_space(1))) unsigned int*)g,
      (__attribute__((address_space(3))) unsigned int*)l, 16, 0, 0);
}

__device__ __forceinline__ ushortT f2bf(float f) {
  __hip_bfloat16 h = __float2bfloat16(f);
  return *reinterpret_cast<ushortT*>(&h);
}

// ---------------------------------------------------------------------------
// Kernel A: fused L2-norm + bf16 convert. One block per row (256 thr x float4).
// ---------------------------------------------------------------------------
__global__ __launch_bounds__(THREADS) void k_prep(const float* __restrict__ x,
                                                  ushortT* __restrict__ xn, int D) {
  __shared__ float red[4];
  const int row = blockIdx.x;
  const int tid = threadIdx.x;
  const int gid = row * (D / 4) + tid;
  const float4 v = reinterpret_cast<const float4*>(x)[gid];
  float s = v.x * v.x + v.y * v.y + v.z * v.z + v.w * v.w;
  #pragma unroll
  for (int off = 32; off; off >>= 1) s += __shfl_xor(s, off);
  if ((tid & 63) == 0) red[tid >> 6] = s;
  __syncthreads();
  const float tot = red[0] + red[1] + red[2] + red[3];
  const float rn = 1.0f / fmaxf(sqrtf(tot), 1e-12f);
  ushort4 o;
  o.x = f2bf(v.x * rn); o.y = f2bf(v.y * rn);
  o.z = f2bf(v.z * rn); o.w = f2bf(v.w * rn);
  reinterpret_cast<ushort4*>(xn)[gid] = o;
}

// ---------------------------------------------------------------------------
// Kernel B: triangular 128x128 bf16 MFMA tiles + dual-orientation circle-loss
// epilogue. Block b -> (bi <= bj). Each acc tile feeds row-partials for the
// bi rows (orientation 1) AND, via symmetry sim(i,j)=sim(j,i), row-partials
// for the bj rows (orientation 2). Staging is laid out in fragment-read
// order: LDS pos lane*16B holds (row=lane&15, kchunk=lane>>4) -> frag reads
// are linear per-lane 16B (conflict-free).
// Pos partials: (max, sum exp(l-max)); neg partials: plain sum exp(l)
// (neg logit <= 60, no overflow). Invalid sentinel -2e30 with max-init
// -1e30 makes masked contributions exactly 0 with no extra mask ops.
// partial[(row*NB + cb)*2 + half] = {mp, sp, 0, sn}
// ---------------------------------------------------------------------------
__global__ __launch_bounds__(THREADS, 2) void k_main_mfma(const ushortT* __restrict__ xn,
                                                          const int* __restrict__ tgt,
                                                          float4* __restrict__ partial,
                                                          int D, int nb) {
  __shared__ ushortT Asm[128 * 32];  // 8 KB
  __shared__ ushortT Bsm[128 * 32];  // 8 KB

  const int tid = threadIdx.x;
  const int lane = tid & 63;
  const int w = tid >> 6;

  // --- triangular decode: b -> (bi, bj), bi <= bj
  const int b = blockIdx.x;
  int bi = (int)((2.f * nb + 1.f -
                  sqrtf((2.f * nb + 1.f) * (2.f * nb + 1.f) - 8.f * (float)b)) * 0.5f);
  while ((bi + 1) * (2 * nb - bi) / 2 <= b) ++bi;
  while (bi * (2 * nb - bi + 1) / 2 > b) --bi;
  const int bj = bi + (b - bi * (2 * nb - bi + 1) / 2);
  const bool isdiag = (bi == bj);

  const int i0 = bi * 128, j0 = bj * 128;
  const int wr = (w >> 1) * 64, wc = (w & 1) * 64;

  // --- staging: lane fetches (row = lane&15, chunk = lane>>4) of its group
  const int sr = lane & 15, sc = lane >> 4;
  const ushortT* gA0 = xn + (size_t)(i0 + w * 16 + sr) * D + sc * 8;
  const ushortT* gA1 = gA0 + (size_t)64 * D;
  const ushortT* gB0 = xn + (size_t)(j0 + w * 16 + sr) * D + sc * 8;
  const ushortT* gB1 = gB0 + (size_t)64 * D;
  ushortT* lA0 = &Asm[w * 512];
  ushortT* lA1 = &Asm[(w + 4) * 512];
  ushortT* lB0 = &Bsm[w * 512];
  ushortT* lB1 = &Bsm[(w + 4) * 512];

  const ushortT* Bbase = isdiag ? Asm : Bsm;
  const int aoff = ((w >> 1) * 4) * 512 + lane * 8;   // ushort index
  const int boff = ((w & 1) * 4) * 512 + lane * 8;

  f32x4 acc[4][4];
  #pragma unroll
  for (int mt = 0; mt < 4; ++mt)
    #pragma unroll
    for (int nt = 0; nt < 4; ++nt)
      acc[mt][nt] = (f32x4){0.f, 0.f, 0.f, 0.f};

  const int kiters = D / 32;
  for (int kk = 0; kk < kiters; ++kk) {
    const size_t ko = (size_t)kk * 32;
    async16(gA0 + ko, lA0);
    async16(gA1 + ko, lA1);
    if (!isdiag) {
      async16(gB0 + ko, lB0);
      async16(gB1 + ko, lB1);
    }
    __syncthreads();
    bf16x8 afr[4], bfr[4];
    #pragma unroll
    for (int mt = 0; mt < 4; ++mt)
      afr[mt] = *reinterpret_cast<const bf16x8*>(&Asm[aoff + mt * 512]);
    #pragma unroll
    for (int nt = 0; nt < 4; ++nt)
      bfr[nt] = *reinterpret_cast<const bf16x8*>(&Bbase[boff + nt * 512]);
    #pragma unroll
    for (int mt = 0; mt < 4; ++mt)
      #pragma unroll
      for (int nt = 0; nt < 4; ++nt)
        acc[mt][nt] = __builtin_amdgcn_mfma_f32_16x16x32_bf16(afr[mt], bfr[nt], acc[mt][nt], 0, 0, 0);
    __syncthreads();
  }

  // --- epilogue. C/D layout: col = lane&15, row = (lane>>4)*4 + reg
  const int q = lane >> 4, c = lane & 15;
  int tj[4];
  #pragma unroll
  for (int nt = 0; nt < 4; ++nt) tj[nt] = tgt[j0 + wc + nt * 16 + c];
  int tir[16];
  #pragma unroll
  for (int mt = 0; mt < 4; ++mt) {
    const int4 t4 = *reinterpret_cast<const int4*>(tgt + i0 + wr + mt * 16 + q * 4);
    tir[mt * 4 + 0] = t4.x; tir[mt * 4 + 1] = t4.y;
    tir[mt * 4 + 2] = t4.z; tir[mt * 4 + 3] = t4.w;
  }

  // orientation 1: rows of bi block, cols of bj block
  #pragma unroll
  for (int mt = 0; mt < 4; ++mt) {
    #pragma unroll
    for (int reg = 0; reg < 4; ++reg) {
      const int i = i0 + wr + mt * 16 + q * 4 + reg;
      const int ti = tir[mt * 4 + reg];
      float m = -1e30f, sn = 0.f;
      float sel[4];
      #pragma unroll
      for (int nt = 0; nt < 4; ++nt) {
        const float s = acc[mt][nt][reg];
        const int j = j0 + wc + nt * 16 + c;
        const bool same = (tj[nt] == ti);
        const bool vpos = same && (j != i);
        const float lp = (fminf(s, 1.25f) - 1.25f) * fmaf(s, 64.f, -48.f);
        const float sv = vpos ? lp : -2e30f;
        sel[nt] = sv;
        m = fmaxf(m, sv);
        const float ln = (fmaxf(s, -0.25f) + 0.25f) * fmaf(s, 64.f, -16.f);
        const float en = __expf(ln);
        sn += same ? 0.f : en;
      }
      #pragma unroll
      for (int off = 1; off < 16; off <<= 1) m = fmaxf(m, __shfl_xor(m, off));
      float sp = 0.f;
      #pragma unroll
      for (int nt = 0; nt < 4; ++nt) sp += __expf(sel[nt] - m);
      #pragma unroll
      for (int off = 1; off < 16; off <<= 1) {
        sp += __shfl_xor(sp, off);
        sn += __shfl_xor(sn, off);
      }
      if (c == 0) {
        float4 o; o.x = m; o.y = sp; o.z = 0.f; o.w = sn;
        partial[((size_t)i * nb + bj) * 2 + (w & 1)] = o;
      }
    }
  }

  // orientation 2: rows of bj block, cols of bi block (off-diagonal only)
  if (!isdiag) {
    #pragma unroll
    for (int nt = 0; nt < 4; ++nt) {
      const int jt = tj[nt];
      const int jrow = j0 + wc + nt * 16 + c;
      float m = -1e30f, sn = 0.f;
      float sel[16];
      #pragma unroll
      for (int mt = 0; mt < 4; ++mt) {
        #pragma unroll
        for (int reg = 0; reg < 4; ++reg) {
          const float s = acc[mt][nt][reg];
          const bool same = (tir[mt * 4 + reg] == jt);  // j != i guaranteed off-diag
          const float lp = (fminf(s, 1.25f) - 1.25f) * fmaf(s, 64.f, -48.f);
          const float sv = same ? lp : -2e30f;
          sel[mt * 4 + reg] = sv;
          m = fmaxf(m, sv);
          const float ln = (fmaxf(s, -0.25f) + 0.25f) * fmaf(s, 64.f, -16.f);
          const float en = __expf(ln);
          sn += same ? 0.f : en;
        }
      }
      m = fmaxf(m, __shfl_xor(m, 16));
      m = fmaxf(m, __shfl_xor(m, 32));
      float sp = 0.f;
      #pragma unroll
      for (int k = 0; k < 16; ++k) sp += __expf(sel[k] - m);
      sp += __shfl_xor(sp, 16); sp += __shfl_xor(sp, 32);
      sn += __shfl_xor(sn, 16); sn += __shfl_xor(sn, 32);
      if (lane < 16) {
        float4 o; o.x = m; o.y = sp; o.z = 0.f; o.w = sn;
        partial[((size_t)jrow * nb + bi) * 2 + (w >> 1)] = o;
      }
    }
  }
}

// ---------------------------------------------------------------------------
// Kernel C: fold 128 partials per row -> row loss. One wave per row.
// ---------------------------------------------------------------------------
__global__ __launch_bounds__(THREADS) void k_reduce(const float4* __restrict__ partial,
                                                    float* __restrict__ row_loss) {
  const int lane = threadIdx.x & 63;
  const int row = blockIdx.x * 4 + (threadIdx.x >> 6);
  const float4 a = partial[(size_t)row * 128 + lane];
  const float4 b = partial[(size_t)row * 128 + 64 + lane];
  float mp = fmaxf(a.x, b.x);
  float sp = a.y * __expf(a.x - mp) + b.y * __expf(b.x - mp);
  float sn = a.w + b.w;
  #pragma unroll
  for (int off = 1; off < 64; off <<= 1) {
    const float m2 = __shfl_xor(mp, off), s2 = __shfl_xor(sp, off);
    const float nm = fmaxf(mp, m2);
    sp = sp * __expf(mp - nm) + s2 * __expf(m2 - nm);
    mp = nm;
    sn += __shfl_xor(sn, off);
  }
  if (lane == 0) {
    float loss = -1.0f;
    if (sp > 0.f && sn > 0.f) {
      const float z = mp + logf(sp) + logf(sn);
      loss = (z > 0.f) ? (z + log1pf(__expf(-z))) : log1pf(__expf(z));
    }
    row_loss[row] = loss;
  }
}

// ---------------------------------------------------------------------------
// Kernel D: masked mean over rows. One block.
// ---------------------------------------------------------------------------
__global__ __launch_bounds__(THREADS) void k_final(const float* __restrict__ row_loss,
                                                   float* __restrict__ out, int B) {
  __shared__ float ssum[4];
  __shared__ float scnt[4];
  const int tid = threadIdx.x;
  float sum = 0.f, cnt = 0.f;
  for (int i = tid; i < B; i += THREADS) {
    const float l = row_loss[i];
    if (l >= 0.f) { sum += l; cnt += 1.f; }
  }
  #pragma unroll
  for (int off = 32; off; off >>= 1) {
    sum += __shfl_xor(sum, off);
    cnt += __shfl_xor(cnt, off);
  }
  if ((tid & 63) == 0) { ssum[tid >> 6] = sum; scnt[tid >> 6] = cnt; }
  __syncthreads();
  if (tid == 0) {
    float ts = 0.f, tc = 0.f;
    #pragma unroll
    for (int w = 0; w < 4; ++w) { ts += ssum[w]; tc += scnt[w]; }
    out[0] = ts / fmaxf(tc, 1.f);
  }
}

// ---------------------------------------------------------------------------
extern "C" void kernel_launch(void* const* d_in, const int* in_sizes, int n_in,
                              void* d_out, int out_size, void* d_ws, size_t ws_size,
                              hipStream_t stream) {
  const float* x = (const float*)d_in[0];
  const int* tgt = (const int*)d_in[1];
  float* out = (float*)d_out;
  const int B = in_sizes[1];
  const int D = in_sizes[0] / B;
  const int nb = B / 128;

  ushortT* xn = (ushortT*)d_ws;                                   // B*D bf16 (16 MB)
  float4* partial = (float4*)((char*)d_ws + (size_t)B * D * 2);   // B*2*nb float4 (16 MB)
  float* row_loss = (float*)((char*)d_ws + (size_t)B * D * 2 + (size_t)B * 2 * nb * 16);

  k_prep<<<B, THREADS, 0, stream>>>(x, xn, D);
  k_main_mfma<<<nb * (nb + 1) / 2, THREADS, 0, stream>>>(xn, tgt, partial, D, nb);
  k_reduce<<<B / 4, THREADS, 0, stream>>>(partial, row_loss);
  k_final<<<1, THREADS, 0, stream>>>(row_loss, out, B);
}